// Round 1
// baseline (332.954 us; speedup 1.0000x reference)
//
#include <hip/hip_runtime.h>

#define BLANK 36
#define NEG -1e30f
#define C_CLASSES 37

__device__ __forceinline__ float logaddexp_f(float a, float b) {
    float m = fmaxf(a, b);
    float d = fabsf(a - b);
    // exp(-d) -> 0 for d huge; both-NEG case returns NEG + log(2) ~= NEG. Fine.
    return m + __logf(1.0f + __expf(-d));
}

// One wave (64 lanes) per batch sample.
// Lanes 0..C-1 hold per-class logits for the log-softmax reduction.
// Lanes 0..S-1 hold alpha[s]; neighbors via __shfl_up, lp_ext via __shfl broadcast.
__global__ __launch_bounds__(256) void ctc_alpha_kernel(
    const float* __restrict__ logits,        // [B, T, C]
    const int*   __restrict__ targets,       // [B * L]
    const int*   __restrict__ input_lengths, // [B]
    const int*   __restrict__ target_lengths,// [B]
    float*       __restrict__ per_sample,    // [B] loss per sample
    int B, int T, int L)
{
    const int wave = (int)((blockIdx.x * blockDim.x + threadIdx.x) >> 6);
    const int lane = threadIdx.x & 63;
    if (wave >= B) return;
    const int b = wave;
    const int S = 2 * L + 1;

    const int tlen = target_lengths[b];
    const int ilen = input_lengths[b];
    const int end_idx = 2 * tlen;

    // Extended label sequence for s = lane
    int ext_s = BLANK;
    if (lane < S && (lane & 1)) ext_s = targets[b * L + (lane >> 1)];
    const int ext_sm2 = __shfl_up(ext_s, 2);
    const bool skip_ok = (lane < S) && (lane >= 2) && (ext_s != BLANK) && (ext_s != ext_sm2);
    const bool valid = lane < (2 * tlen + 1);

    const float* lg = logits + (size_t)b * T * C_CLASSES;

    float alpha   = NEG;
    float final_v = NEG;

    for (int t = 0; t < T; ++t) {
        // ---- log-softmax over C classes (lanes 0..C-1) ----
        float x = (lane < C_CLASSES) ? lg[t * C_CLASSES + lane] : -3.0e38f;
        float mx = x;
        #pragma unroll
        for (int o = 32; o > 0; o >>= 1) mx = fmaxf(mx, __shfl_xor(mx, o));
        float e = (lane < C_CLASSES) ? __expf(x - mx) : 0.0f;
        float se = e;
        #pragma unroll
        for (int o = 32; o > 0; o >>= 1) se += __shfl_xor(se, o);
        const float lp  = x - mx - __logf(se);   // log-softmax, valid for lane < C
        const float lpe = __shfl(lp, ext_s);     // lp_ext[t][s] for s = lane

        // ---- alpha recurrence ----
        float newa;
        if (t == 0) {
            newa = (lane <= 1) ? lpe : NEG;
        } else {
            float a1 = __shfl_up(alpha, 1);
            if (lane == 0) a1 = NEG;
            float a2 = __shfl_up(alpha, 2);
            if (!skip_ok) a2 = NEG;
            newa = logaddexp_f(logaddexp_f(alpha, a1), a2) + lpe;
        }
        if (!valid) newa = NEG;
        alpha = newa;

        if (ilen == t + 1) {
            const float e1 = __shfl(alpha, end_idx);
            const float e2 = __shfl(alpha, end_idx - 1);
            final_v = logaddexp_f(e1, e2);
        }
    }

    if (lane == 0) per_sample[b] = -final_v / (float)tlen;
}

// Deterministic mean over B per-sample losses (single block).
__global__ __launch_bounds__(256) void reduce_mean_kernel(
    const float* __restrict__ ps, float* __restrict__ out, int B)
{
    float s = 0.0f;
    for (int i = threadIdx.x; i < B; i += 256) s += ps[i];
    #pragma unroll
    for (int o = 32; o > 0; o >>= 1) s += __shfl_xor(s, o);
    __shared__ float sm[4];
    const int w = threadIdx.x >> 6, l = threadIdx.x & 63;
    if (l == 0) sm[w] = s;
    __syncthreads();
    if (threadIdx.x == 0) {
        out[0] = (sm[0] + sm[1] + sm[2] + sm[3]) / (float)B;
    }
}

extern "C" void kernel_launch(void* const* d_in, const int* in_sizes, int n_in,
                              void* d_out, int out_size, void* d_ws, size_t ws_size,
                              hipStream_t stream) {
    const float* logits         = (const float*)d_in[0];
    const int*   targets        = (const int*)d_in[1];
    const int*   input_lengths  = (const int*)d_in[2];
    const int*   target_lengths = (const int*)d_in[3];

    const int B = in_sizes[2];                 // 2048
    const int L = in_sizes[1] / B;             // 16
    const int T = in_sizes[0] / (B * C_CLASSES); // 256

    float* per_sample = (float*)d_ws;          // B floats of scratch
    float* out = (float*)d_out;

    const int waves_per_block = 4;             // 256 threads
    const int nblocks = (B + waves_per_block - 1) / waves_per_block;
    ctc_alpha_kernel<<<nblocks, 256, 0, stream>>>(
        logits, targets, input_lengths, target_lengths, per_sample, B, T, L);
    reduce_mean_kernel<<<1, 256, 0, stream>>>(per_sample, out, B);
}

// Round 2
// 193.273 us; speedup vs baseline: 1.7227x; 1.7227x over previous
//
#include <hip/hip_runtime.h>

#define BLANK 36
#define NEG -1e30f
#define CC 37

__device__ __forceinline__ float logaddexp_f(float a, float b) {
    float m = fmaxf(a, b);
    float d = fabsf(a - b);
    return m + __logf(1.0f + __expf(-d));
}

// ---------------- Kernel A: per-(b,t) logsumexp over C=37 classes ----------
// One thread per (b,t). Massively parallel (B*T = 524k threads), memory-bound.
__global__ __launch_bounds__(256) void lse_kernel(
    const float* __restrict__ logits,  // [B*T, C]
    float*       __restrict__ denom,   // [B*T]
    int N)
{
    const int i = blockIdx.x * 256 + threadIdx.x;
    if (i >= N) return;
    const float* p = logits + (size_t)i * CC;
    float x[CC];
    #pragma unroll
    for (int c = 0; c < CC; ++c) x[c] = p[c];
    float m = x[0];
    #pragma unroll
    for (int c = 1; c < CC; ++c) m = fmaxf(m, x[c]);
    float s = 0.0f;
    #pragma unroll
    for (int c = 0; c < CC; ++c) s += __expf(x[c] - m);
    denom[i] = m + __logf(s);
}

// ---------------- Kernel B: alpha recurrence, one wave per sample ----------
// Per-t chain is now only: 2 parallel shfl_up + max3 + 3 parallel exp + log.
// The x/denom loads for step t+1 are issued before the step-t chain (prefetch).
__global__ __launch_bounds__(256) void ctc_alpha2_kernel(
    const float* __restrict__ logits,        // [B, T, C]
    const float* __restrict__ denom,         // [B, T]
    const int*   __restrict__ targets,       // [B * L]
    const int*   __restrict__ input_lengths, // [B]
    const int*   __restrict__ target_lengths,// [B]
    float*       __restrict__ per_sample,    // [B]
    int B, int T, int L)
{
    const int wave = (int)((blockIdx.x * blockDim.x + threadIdx.x) >> 6);
    const int lane = threadIdx.x & 63;
    if (wave >= B) return;
    const int b = wave;
    const int S = 2 * L + 1;

    const int tlen = target_lengths[b];
    const int ilen = input_lengths[b];
    const int end_idx = 2 * tlen;

    int ext_s = BLANK;  // ext_s < CC always, so loads below are in-bounds for every lane
    if (lane < S && (lane & 1)) ext_s = targets[b * L + (lane >> 1)];
    const int ext_sm2 = __shfl_up(ext_s, 2);
    const bool skip_ok = (lane < S) && (lane >= 2) && (ext_s != BLANK) && (ext_s != ext_sm2);
    const bool valid = lane < (2 * tlen + 1);

    const float* lg = logits + (size_t)b * T * CC;
    const float* dn = denom + (size_t)b * T;

    // t = 0
    float x_cur = lg[ext_s];
    float d_cur = dn[0];
    // prefetch t = 1
    float x_nx = lg[CC + ext_s];
    float d_nx = dn[1];

    float final_v = NEG;
    float alpha = (valid && lane <= 1) ? (x_cur - d_cur) : NEG;
    if (ilen == 1) {
        const float e1 = __shfl(alpha, end_idx);
        const float e2 = __shfl(alpha, end_idx - 1);
        final_v = logaddexp_f(e1, e2);
    }

    for (int t = 1; t < T; ++t) {
        x_cur = x_nx;
        d_cur = d_nx;
        if (t + 1 < T) {  // issue next loads before the dependent chain
            x_nx = lg[(size_t)(t + 1) * CC + ext_s];
            d_nx = dn[t + 1];
        }
        const float lpe = x_cur - d_cur;

        float a1 = __shfl_up(alpha, 1);
        if (lane == 0) a1 = NEG;
        float a2 = __shfl_up(alpha, 2);
        if (!skip_ok) a2 = NEG;

        // 3-way logsumexp: shorter serial chain than nested logaddexp
        const float m = fmaxf(fmaxf(alpha, a1), a2);
        const float s = __expf(alpha - m) + __expf(a1 - m) + __expf(a2 - m);
        float na = m + __logf(s) + lpe;
        alpha = valid ? na : NEG;

        if (ilen == t + 1) {  // wave-uniform branch
            const float e1 = __shfl(alpha, end_idx);
            const float e2 = __shfl(alpha, end_idx - 1);
            final_v = logaddexp_f(e1, e2);
        }
    }

    if (lane == 0) per_sample[b] = -final_v / (float)tlen;
}

// ---------------- Fallback: round-1 monolithic kernel (ws too small) -------
__global__ __launch_bounds__(256) void ctc_alpha_mono_kernel(
    const float* __restrict__ logits,
    const int*   __restrict__ targets,
    const int*   __restrict__ input_lengths,
    const int*   __restrict__ target_lengths,
    float*       __restrict__ per_sample,
    int B, int T, int L)
{
    const int wave = (int)((blockIdx.x * blockDim.x + threadIdx.x) >> 6);
    const int lane = threadIdx.x & 63;
    if (wave >= B) return;
    const int b = wave;
    const int S = 2 * L + 1;
    const int tlen = target_lengths[b];
    const int ilen = input_lengths[b];
    const int end_idx = 2 * tlen;
    int ext_s = BLANK;
    if (lane < S && (lane & 1)) ext_s = targets[b * L + (lane >> 1)];
    const int ext_sm2 = __shfl_up(ext_s, 2);
    const bool skip_ok = (lane < S) && (lane >= 2) && (ext_s != BLANK) && (ext_s != ext_sm2);
    const bool valid = lane < (2 * tlen + 1);
    const float* lg = logits + (size_t)b * T * CC;
    float alpha = NEG, final_v = NEG;
    for (int t = 0; t < T; ++t) {
        float x = (lane < CC) ? lg[t * CC + lane] : -3.0e38f;
        float mx = x;
        #pragma unroll
        for (int o = 32; o > 0; o >>= 1) mx = fmaxf(mx, __shfl_xor(mx, o));
        float e = (lane < CC) ? __expf(x - mx) : 0.0f;
        float se = e;
        #pragma unroll
        for (int o = 32; o > 0; o >>= 1) se += __shfl_xor(se, o);
        const float lp = x - mx - __logf(se);
        const float lpe = __shfl(lp, ext_s);
        float newa;
        if (t == 0) {
            newa = (lane <= 1) ? lpe : NEG;
        } else {
            float a1 = __shfl_up(alpha, 1);
            if (lane == 0) a1 = NEG;
            float a2 = __shfl_up(alpha, 2);
            if (!skip_ok) a2 = NEG;
            newa = logaddexp_f(logaddexp_f(alpha, a1), a2) + lpe;
        }
        if (!valid) newa = NEG;
        alpha = newa;
        if (ilen == t + 1) {
            const float e1 = __shfl(alpha, end_idx);
            const float e2 = __shfl(alpha, end_idx - 1);
            final_v = logaddexp_f(e1, e2);
        }
    }
    if (lane == 0) per_sample[b] = -final_v / (float)tlen;
}

// ---------------- Deterministic mean over B samples ------------------------
__global__ __launch_bounds__(256) void reduce_mean_kernel(
    const float* __restrict__ ps, float* __restrict__ out, int B)
{
    float s = 0.0f;
    for (int i = threadIdx.x; i < B; i += 256) s += ps[i];
    #pragma unroll
    for (int o = 32; o > 0; o >>= 1) s += __shfl_xor(s, o);
    __shared__ float sm[4];
    const int w = threadIdx.x >> 6, l = threadIdx.x & 63;
    if (l == 0) sm[w] = s;
    __syncthreads();
    if (threadIdx.x == 0) {
        out[0] = (sm[0] + sm[1] + sm[2] + sm[3]) / (float)B;
    }
}

extern "C" void kernel_launch(void* const* d_in, const int* in_sizes, int n_in,
                              void* d_out, int out_size, void* d_ws, size_t ws_size,
                              hipStream_t stream) {
    const float* logits         = (const float*)d_in[0];
    const int*   targets        = (const int*)d_in[1];
    const int*   input_lengths  = (const int*)d_in[2];
    const int*   target_lengths = (const int*)d_in[3];

    const int B = in_sizes[2];
    const int L = in_sizes[1] / B;
    const int T = in_sizes[0] / (B * CC);
    const int N = B * T;

    float* per_sample = (float*)d_ws;          // B floats
    float* denom      = per_sample + B;        // B*T floats
    float* out        = (float*)d_out;

    const size_t ws_needed = (size_t)(B + N) * sizeof(float);
    const int nblocks_alpha = (B * 64 + 255) / 256;

    if (ws_size >= ws_needed && T >= 2) {
        lse_kernel<<<(N + 255) / 256, 256, 0, stream>>>(logits, denom, N);
        ctc_alpha2_kernel<<<nblocks_alpha, 256, 0, stream>>>(
            logits, denom, targets, input_lengths, target_lengths, per_sample, B, T, L);
    } else {
        ctc_alpha_mono_kernel<<<nblocks_alpha, 256, 0, stream>>>(
            logits, targets, input_lengths, target_lengths, per_sample, B, T, L);
    }
    reduce_mean_kernel<<<1, 256, 0, stream>>>(per_sample, out, B);
}